// Round 1
// baseline (1430.868 us; speedup 1.0000x reference)
//
#include <hip/hip_runtime.h>
#include <stdint.h>

// MoE top-2 routed SwiGLU. B=2,S=1024 -> T=2048 tokens, D=2048, F=8192, E=4, K=2.
// R3: counted-vmcnt pipelined GEMMs (8-wave, triple-buffered LDS, setprio around
// MFMA clusters, never vmcnt(0) in main loop) + vectorized transpose pass.

#define T_TOK 2048
#define DM    2048
#define FF    8192
#define DF    ((size_t)DM * FF)

typedef unsigned short u16;
typedef short short8 __attribute__((ext_vector_type(8)));
typedef float f32x4  __attribute__((ext_vector_type(4)));

#define GLL16(g, l) __builtin_amdgcn_global_load_lds( \
    (const __attribute__((address_space(1))) void*)(g), \
    (__attribute__((address_space(3))) void*)(l), 16, 0, 0)

#define BARRIER() do { asm volatile("" ::: "memory"); __builtin_amdgcn_s_barrier(); asm volatile("" ::: "memory"); } while (0)
#define LGK0()    do { asm volatile("s_waitcnt lgkmcnt(0)" ::: "memory"); __builtin_amdgcn_sched_barrier(0); } while (0)
#define VMW(N)    asm volatile("s_waitcnt vmcnt(" #N ")" ::: "memory")
#define PRIO1()   __builtin_amdgcn_s_setprio(1)
#define PRIO0()   __builtin_amdgcn_s_setprio(0)

__device__ __forceinline__ u16 f2bf(float f) {
  uint32_t x = __float_as_uint(f);
  x += 0x7fffu + ((x >> 16) & 1u);
  return (u16)(x >> 16);
}

// ---------------- router: probs + top2 + slot assignment ----------------
__global__ __launch_bounds__(256) void router_kernel(
    const float* __restrict__ x, const float* __restrict__ Wr,
    int* __restrict__ counts, int* __restrict__ tok, float* __restrict__ gate)
{
  int t = blockIdx.x * 4 + (threadIdx.x >> 6);   // one wave per token
  int l = threadIdx.x & 63;
  const float* xr = x + (size_t)t * DM;
  const float4* wr4 = (const float4*)Wr;         // Wr row d = 4 consecutive floats
  float a0 = 0.f, a1 = 0.f, a2 = 0.f, a3 = 0.f;
  for (int d = l; d < DM; d += 64) {
    float xv = xr[d];
    float4 w = wr4[d];
    a0 += xv * w.x; a1 += xv * w.y; a2 += xv * w.z; a3 += xv * w.w;
  }
  #pragma unroll
  for (int off = 32; off > 0; off >>= 1) {
    a0 += __shfl_down(a0, off);
    a1 += __shfl_down(a1, off);
    a2 += __shfl_down(a2, off);
    a3 += __shfl_down(a3, off);
  }
  if (l == 0) {
    float lg[4] = {a0, a1, a2, a3};
    float m = fmaxf(fmaxf(lg[0], lg[1]), fmaxf(lg[2], lg[3]));
    float p[4], s = 0.f;
    #pragma unroll
    for (int e = 0; e < 4; ++e) { p[e] = __expf(lg[e] - m); s += p[e]; }
    #pragma unroll
    for (int e = 0; e < 4; ++e) p[e] /= s;
    int i0 = 0;
    #pragma unroll
    for (int e = 1; e < 4; ++e) if (p[e] > p[i0]) i0 = e;      // ties -> lower idx, matches lax.top_k
    int i1 = (i0 == 0) ? 1 : 0;
    #pragma unroll
    for (int e = 0; e < 4; ++e) if (e != i0 && p[e] > p[i1]) i1 = e;
    int s0 = atomicAdd(&counts[i0], 1);
    tok[i0 * T_TOK + s0] = t; gate[i0 * T_TOK + s0] = p[i0];
    int s1 = atomicAdd(&counts[i1], 1);
    tok[i1 * T_TOK + s1] = t; gate[i1 * T_TOK + s1] = p[i1];
  }
}

// ---------------- gather token rows -> per-expert contiguous bf16 A ----------------
__global__ __launch_bounds__(256) void gather_kernel(
    const float* __restrict__ x, const int* __restrict__ counts,
    const int* __restrict__ tok, u16* __restrict__ Xe)
{
  int e = blockIdx.x >> 11;
  int slot = blockIdx.x & (T_TOK - 1);
  if (slot >= counts[e]) return;
  int t = tok[e * T_TOK + slot];
  const float4* src = (const float4*)(x + (size_t)t * DM);
  u16* dst = Xe + ((size_t)e * T_TOK + slot) * DM;
  int i = threadIdx.x;                           // 256 thr x 8 elems = 2048
  float4 a = src[i * 2], b = src[i * 2 + 1];
  union { u16 h[8]; uint4 q; } v;
  v.h[0] = f2bf(a.x); v.h[1] = f2bf(a.y); v.h[2] = f2bf(a.z); v.h[3] = f2bf(a.w);
  v.h[4] = f2bf(b.x); v.h[5] = f2bf(b.y); v.h[6] = f2bf(b.z); v.h[7] = f2bf(b.w);
  *(uint4*)(dst + i * 8) = v.q;
}

// ---------------- transpose + fp32->bf16 convert, ALL 12 jobs, vectorized ----------------
// jobs 0-3: Wg[e] [D,F]->[F,D]; 4-7: Wu[e]; 8-11: Wd[e] [F,D]->[D,F]
__global__ __launch_bounds__(256) void trans_cvt_all(
    const float* __restrict__ Wg, const float* __restrict__ Wu, const float* __restrict__ Wd,
    u16* __restrict__ Wgt, u16* __restrict__ Wut, u16* __restrict__ Wdt)
{
  int j = blockIdx.y;
  const float* src; u16* dst; int R, C, clog;
  if (j < 4)      { src = Wg + (size_t)j * DF;       dst = Wgt + (size_t)j * DF;       R = DM; C = FF; clog = 7; }
  else if (j < 8) { src = Wu + (size_t)(j - 4) * DF; dst = Wut + (size_t)(j - 4) * DF; R = DM; C = FF; clog = 7; }
  else            { src = Wd + (size_t)(j - 8) * DF; dst = Wdt + (size_t)(j - 8) * DF; R = FF; C = DM; clog = 5; }
  int bx = blockIdx.x;
  int c0 = (bx & ((1 << clog) - 1)) * 64;
  int r0 = (bx >> clog) * 64;

  __shared__ float tile[64][68];                 // stride 68: rows 16B-aligned (272B)
  int tid = threadIdx.x;
  const float4* s4 = (const float4*)(src + (size_t)r0 * C + c0);
  const int cq = C >> 2;
  #pragma unroll
  for (int k2 = 0; k2 < 4; ++k2) {               // 1024 float4 = 64x64 tile, 16B/lane
    int f = tid + 256 * k2;
    int row = f >> 4, c4 = f & 15;
    float4 v = s4[(size_t)row * cq + c4];
    *(float4*)&tile[row][c4 * 4] = v;
  }
  __syncthreads();
  int ro = tid >> 2, seg = tid & 3;              // out row ro (=src col), 16 elems/seg
  union { u16 h[16]; uint4 q[2]; } v;
  #pragma unroll
  for (int i = 0; i < 16; ++i) v.h[i] = f2bf(tile[seg * 16 + i][ro]);
  u16* drow = dst + (size_t)(c0 + ro) * R + r0 + seg * 16;
  *(uint4*)(drow)     = v.q[0];
  *(uint4*)(drow + 8) = v.q[1];
}

// ---------------- GEMM12 (all experts): H = silu(A@WgT') * (A@WuT') ----------------
// 128x128 dual-B tile, 8 waves (2x4), BK=64, triple-buffered LDS (144 KiB),
// 2 phases/K-tile, counted vmcnt (10/8 steady; 6/2, 0 tail). grid: x=F/128, y=e*16+rb.
__global__ __launch_bounds__(512, 2) void gemm12_kernel(
    const u16* __restrict__ XeB, const u16* __restrict__ WgtB, const u16* __restrict__ WutB,
    u16* __restrict__ HB, const int* __restrict__ counts)
{
  const int e  = blockIdx.y >> 4;
  const int rb = blockIdx.y & 15;
  const int cnt = counts[e];
  if (rb * 128 >= cnt) return;
  const u16* Ag  = XeB  + (size_t)e * T_TOK * DM + (size_t)rb * 128 * DM;
  const u16* Bgg = WgtB + (size_t)e * DF + (size_t)blockIdx.x * 128 * DM;
  const u16* Bug = WutB + (size_t)e * DF + (size_t)blockIdx.x * 128 * DM;
  u16* H = HB + (size_t)e * T_TOK * FF;

  __shared__ __align__(16) u16 ldsT[3][3][128 * 64];   // [buf][A,Bg,Bu]

  const int tid = threadIdx.x, l = tid & 63, w = tid >> 6;
  const int wm = w & 1, wn = w >> 1;
  const int cg = (l & 7) ^ (l >> 3);             // global-side XOR swizzle (LDS dst linear)
  const size_t so0 = (size_t)(w * 16 + (l >> 3)) * DM + cg * 8;
  const size_t so1 = so0 + (size_t)8 * DM;
  const int lo0 = w * 1024;                      // (w*16)*64 u16
  const int lo1 = lo0 + 512;

  int fmA[4], fnB[2], c2k[2];
  #pragma unroll
  for (int m = 0; m < 4; ++m) fmA[m] = (wm * 64 + m * 16 + (l & 15)) * 64;
  #pragma unroll
  for (int n = 0; n < 2; ++n) fnB[n] = (wn * 32 + n * 16 + (l & 15)) * 64;
  c2k[0] = ((l >> 4) ^ (l & 7)) * 8;
  c2k[1] = ((4 + (l >> 4)) ^ (l & 7)) * 8;

  f32x4 accg[4][2] = {};
  f32x4 accu[4][2] = {};

  #define G12_STAGE(ti, which, srcp) do { \
    u16* d_ = &ldsT[(ti) % 3][which][0]; \
    GLL16((srcp) + (size_t)(ti) * 64 + so0, d_ + lo0); \
    GLL16((srcp) + (size_t)(ti) * 64 + so1, d_ + lo1); } while (0)

  // prologue — FIFO order matters for the vmcnt accounting below
  G12_STAGE(0, 0, Ag); G12_STAGE(0, 1, Bgg);
  G12_STAGE(0, 2, Bug);
  G12_STAGE(1, 0, Ag); G12_STAGE(1, 1, Bgg);
  G12_STAGE(1, 2, Bug);
  VMW(8);                                        // tile0 A,Bg landed (Bu0,A1,Bg1,Bu1 in flight)
  BARRIER();

  #define G12_KTILE(T, ISSUE, KA, KB) do { \
    const u16* a_  = &ldsT[(T) % 3][0][0]; \
    const u16* bg_ = &ldsT[(T) % 3][1][0]; \
    const u16* bu_ = &ldsT[(T) % 3][2][0]; \
    short8 af[2][4], bgf[2][2], buf2[2][2]; \
    _Pragma("unroll") \
    for (int kk = 0; kk < 2; ++kk) { \
      _Pragma("unroll") \
      for (int m = 0; m < 4; ++m) af[kk][m] = *(const short8*)&a_[fmA[m] + c2k[kk]]; \
      _Pragma("unroll") \
      for (int n = 0; n < 2; ++n) bgf[kk][n] = *(const short8*)&bg_[fnB[n] + c2k[kk]]; \
    } \
    if (ISSUE) { G12_STAGE((T) + 2, 0, Ag); G12_STAGE((T) + 2, 1, Bgg); } \
    BARRIER(); LGK0(); PRIO1(); \
    _Pragma("unroll") \
    for (int kk = 0; kk < 2; ++kk) \
      _Pragma("unroll") \
      for (int m = 0; m < 4; ++m) \
        _Pragma("unroll") \
        for (int n = 0; n < 2; ++n) \
          accg[m][n] = __builtin_amdgcn_mfma_f32_16x16x32_bf16(af[kk][m], bgf[kk][n], accg[m][n], 0, 0, 0); \
    PRIO0(); VMW(KA); BARRIER(); \
    _Pragma("unroll") \
    for (int kk = 0; kk < 2; ++kk) { \
      _Pragma("unroll") \
      for (int n = 0; n < 2; ++n) buf2[kk][n] = *(const short8*)&bu_[fnB[n] + c2k[kk]]; \
    } \
    if (ISSUE) { G12_STAGE((T) + 2, 2, Bug); } \
    BARRIER(); LGK0(); PRIO1(); \
    _Pragma("unroll") \
    for (int kk = 0; kk < 2; ++kk) \
      _Pragma("unroll") \
      for (int m = 0; m < 4; ++m) \
        _Pragma("unroll") \
        for (int n = 0; n < 2; ++n) \
          accu[m][n] = __builtin_amdgcn_mfma_f32_16x16x32_bf16(af[kk][m], buf2[kk][n], accu[m][n], 0, 0, 0); \
    PRIO0(); VMW(KB); BARRIER(); \
  } while (0)

  for (int t = 0; t < 30; ++t) G12_KTILE(t, 1, 10, 8);   // NT = DM/64 = 32
  G12_KTILE(30, 0, 6, 2);
  G12_KTILE(31, 0, 0, 0);

  // epilogue: C/D layout col=lane&15, row=(lane>>4)*4+reg
  const int rloc = rb * 128 + wm * 64 + ((l >> 4) << 2);
  const int cb   = blockIdx.x * 128 + wn * 32 + (l & 15);
  #pragma unroll
  for (int m = 0; m < 4; ++m)
    #pragma unroll
    for (int i = 0; i < 4; ++i) {
      u16* hrow = H + (size_t)(rloc + m * 16 + i) * FF + cb;
      #pragma unroll
      for (int n = 0; n < 2; ++n) {
        float g = accg[m][n][i], u = accu[m][n][i];
        hrow[n * 16] = f2bf((g / (1.f + __expf(-g))) * u);   // silu(g)*u
      }
    }
}

// ---------------- GEMM3: out[tok[r]] += gate[r]*(H@WdT') ----------------
// 128x256 tile, 8 waves, BK=64, triple-buffered (144 KiB), one vmcnt(6)/K-tile.
// grid: x=DM/256=8, y=e*16+rb  (~256 active blocks = 1 block/CU).
__global__ __launch_bounds__(512, 2) void gemm3_kernel(
    const u16* __restrict__ HB, const u16* __restrict__ WdtB,
    float* __restrict__ out, const int* __restrict__ counts,
    const int* __restrict__ tokB, const float* __restrict__ gateB)
{
  const int e  = blockIdx.y >> 4;
  const int rb = blockIdx.y & 15;
  const int cnt = counts[e];
  if (rb * 128 >= cnt) return;
  const u16* Ag = HB   + (size_t)e * T_TOK * FF + (size_t)rb * 128 * FF;
  const u16* Bgp = WdtB + (size_t)e * DF + (size_t)blockIdx.x * 256 * FF;
  const int* tokd = tokB + e * T_TOK;
  const float* gated = gateB + e * T_TOK;

  __shared__ __align__(16) u16 ldsA[3][128 * 64];
  __shared__ __align__(16) u16 ldsB[3][256 * 64];

  const int tid = threadIdx.x, l = tid & 63, w = tid >> 6;
  const int wm = w & 1, wn = w >> 1;
  const int cg = (l & 7) ^ (l >> 3);
  const size_t so0 = (size_t)(w * 16 + (l >> 3)) * FF + cg * 8;
  const size_t so1 = so0 + (size_t)8 * FF;
  const int lo0 = w * 1024, lo1 = lo0 + 512;

  int fmA[4], fnB_[4], c2k[2];
  #pragma unroll
  for (int m = 0; m < 4; ++m) fmA[m] = (wm * 64 + m * 16 + (l & 15)) * 64;
  #pragma unroll
  for (int n = 0; n < 4; ++n) fnB_[n] = (wn * 64 + n * 16 + (l & 15)) * 64;
  c2k[0] = ((l >> 4) ^ (l & 7)) * 8;
  c2k[1] = ((4 + (l >> 4)) ^ (l & 7)) * 8;

  f32x4 acc[4][4] = {};

  #define G3_STAGE_A(ti) do { u16* d_ = &ldsA[(ti) % 3][0]; \
    GLL16(Ag + (size_t)(ti) * 64 + so0, d_ + lo0); \
    GLL16(Ag + (size_t)(ti) * 64 + so1, d_ + lo1); } while (0)
  #define G3_STAGE_B(ti, half) do { u16* d_ = &ldsB[(ti) % 3][(half) * (128 * 64)]; \
    GLL16(Bgp + (size_t)(half) * 128 * FF + (size_t)(ti) * 64 + so0, d_ + lo0); \
    GLL16(Bgp + (size_t)(half) * 128 * FF + (size_t)(ti) * 64 + so1, d_ + lo1); } while (0)

  // prologue FIFO: [A0,B0h0][B0h1][A1,B1h0][B1h1]
  G3_STAGE_A(0); G3_STAGE_B(0, 0);
  G3_STAGE_B(0, 1);
  G3_STAGE_A(1); G3_STAGE_B(1, 0);
  G3_STAGE_B(1, 1);
  VMW(6);                                        // tile0 landed (tile1's 6 loads in flight)
  BARRIER();

  #define G3_KTILE(T, ISSUE, KB) do { \
    const u16* a_ = &ldsA[(T) % 3][0]; const u16* b_ = &ldsB[(T) % 3][0]; \
    short8 af[4], bf[4]; \
    _Pragma("unroll") \
    for (int m = 0; m < 4; ++m) af[m] = *(const short8*)&a_[fmA[m] + c2k[0]]; \
    _Pragma("unroll") \
    for (int n = 0; n < 4; ++n) bf[n] = *(const short8*)&b_[fnB_[n] + c2k[0]]; \
    if (ISSUE) { G3_STAGE_A((T) + 2); G3_STAGE_B((T) + 2, 0); } \
    BARRIER(); LGK0(); PRIO1(); \
    _Pragma("unroll") \
    for (int m = 0; m < 4; ++m) \
      _Pragma("unroll") \
      for (int n = 0; n < 4; ++n) \
        acc[m][n] = __builtin_amdgcn_mfma_f32_16x16x32_bf16(af[m], bf[n], acc[m][n], 0, 0, 0); \
    PRIO0(); BARRIER(); \
    _Pragma("unroll") \
    for (int m = 0; m < 4; ++m) af[m] = *(const short8*)&a_[fmA[m] + c2k[1]]; \
    _Pragma("unroll") \
    for (int n = 0; n < 4; ++n) bf[n] = *(const short8*)&b_[fnB_[n] + c2k[1]]; \
    if (ISSUE) { G3_STAGE_B((T) + 2, 1); } \
    BARRIER(); LGK0(); PRIO1(); \
    _Pragma("unroll") \
    for (int m = 0; m < 4; ++m) \
      _Pragma("unroll") \
      for (int n = 0; n < 4; ++n) \
        acc[m][n] = __builtin_amdgcn_mfma_f32_16x16x32_bf16(af[m], bf[n], acc[m][n], 0, 0, 0); \
    PRIO0(); VMW(KB); BARRIER(); \
  } while (0)

  for (int t = 0; t < 126; ++t) G3_KTILE(t, 1, 6);       // NT = FF/64 = 128
  G3_KTILE(126, 0, 0);
  G3_KTILE(127, 0, 0);

  const int rloc = wm * 64 + ((l >> 4) << 2);
  const int cb   = blockIdx.x * 256 + wn * 64 + (l & 15);
  #pragma unroll
  for (int m = 0; m < 4; ++m)
    #pragma unroll
    for (int i = 0; i < 4; ++i) {
      int r = rb * 128 + rloc + m * 16 + i;
      if (r < cnt) {
        float gv = gated[r];
        float* orow = out + (size_t)tokd[r] * DM + cb;
        #pragma unroll
        for (int n = 0; n < 4; ++n)
          atomicAdd(orow + n * 16, acc[m][n][i] * gv);   // 2 writers/elem (top-2 experts)
      }
    }
}

extern "C" void kernel_launch(void* const* d_in, const int* in_sizes, int n_in,
                              void* d_out, int out_size, void* d_ws, size_t ws_size,
                              hipStream_t stream) {
  (void)in_sizes; (void)n_in; (void)out_size; (void)ws_size;
  const float* x  = (const float*)d_in[0];
  const float* Wr = (const float*)d_in[1];
  const float* Wg = (const float*)d_in[2];
  const float* Wu = (const float*)d_in[3];
  const float* Wd = (const float*)d_in[4];
  float* out = (float*)d_out;

  char* ws = (char*)d_ws;
  int*   counts = (int*)(ws);                            // 4 ints
  int*   tok    = (int*)(ws + 1024);                     // E*T ints
  float* gate   = (float*)(ws + 1024 + 4 * T_TOK * 4);
  u16*   Xe     = (u16*)(ws + 1024 + 2 * 4 * T_TOK * 4); // [E][T][D]  33.5 MB
  u16*   Wgt    = Xe  + (size_t)4 * T_TOK * DM;          // [E][F][D] 134 MB
  u16*   Wut    = Wgt + 4 * DF;                          // [E][F][D] 134 MB
  u16*   Wdt    = Wut + 4 * DF;                          // [E][D][F] 134 MB
  u16*   H      = Wdt + 4 * DF;                          // [E][T][F] 134 MB  (total ~570 MB < 1 GiB ws)

  hipMemsetAsync(out, 0, (size_t)T_TOK * DM * sizeof(float), stream);
  hipMemsetAsync(counts, 0, 4 * sizeof(int), stream);

  router_kernel<<<T_TOK / 4, 256, 0, stream>>>(x, Wr, counts, tok, gate);
  gather_kernel<<<4 * T_TOK, 256, 0, stream>>>(x, counts, tok, Xe);
  trans_cvt_all<<<dim3(4096, 12), 256, 0, stream>>>(Wg, Wu, Wd, Wgt, Wut, Wdt);
  gemm12_kernel<<<dim3(FF / 128, 64), 512, 0, stream>>>(Xe, Wgt, Wut, H, counts);
  gemm3_kernel<<<dim3(DM / 256, 64), 512, 0, stream>>>(H, Wdt, out, counts, tok, gate);
}